// Round 1
// baseline (6496.478 us; speedup 1.0000x reference)
//
#include <hip/hip_runtime.h>

// Problem constants (from reference): B=64, D=1024, P=512, K=64, L=24
#define B_ 64
#define D_ 1024
#define P_ 512
#define K_ 64
#define L_ 24

// Generic TN GEMM: C[m][n] = sum_k A[k][m] * (scale?scale[k]:1) * B[k][n]
// 64x64 tile per WG, 256 threads, 4x4 microtile, K-step 16 staged in LDS.
// All operand reads are contiguous in the fast index (outer-product form).
__global__ __launch_bounds__(256) void gemm_tn(
    const float* __restrict__ A, int lda, long sA,
    const float* __restrict__ B, int ldb, long sB,
    float* __restrict__ C, int ldc, long sC,
    int Kd, const float* __restrict__ scale)
{
    const float* Ab = A + (long)blockIdx.z * sA;
    const float* Bb = B + (long)blockIdx.z * sB;
    float*       Cb = C + (long)blockIdx.z * sC;
    const int i0 = blockIdx.y * 64;
    const int j0 = blockIdx.x * 64;

    __shared__ float As[16][64];
    __shared__ float Bs[16][64];

    const int tid = threadIdx.x;           // 0..255
    const int tx = tid & 15, ty = tid >> 4;
    const int ld = tid >> 4;               // k-row within tile (0..15)
    const int lc = (tid & 15) * 4;         // col within tile (float4)

    float acc[4][4] = {};

    for (int k0 = 0; k0 < Kd; k0 += 16) {
        float4 av = *(const float4*)&Ab[(long)(k0 + ld) * lda + i0 + lc];
        float4 bv = *(const float4*)&Bb[(long)(k0 + ld) * ldb + j0 + lc];
        if (scale) {
            float s = scale[k0 + ld];
            bv.x *= s; bv.y *= s; bv.z *= s; bv.w *= s;
        }
        __syncthreads();   // previous iteration's LDS reads complete
        *(float4*)&As[ld][lc] = av;
        *(float4*)&Bs[ld][lc] = bv;
        __syncthreads();
        #pragma unroll
        for (int kk = 0; kk < 16; kk++) {
            float4 a4 = *(const float4*)&As[kk][ty * 4];
            float4 b4 = *(const float4*)&Bs[kk][tx * 4];
            float aa[4] = {a4.x, a4.y, a4.z, a4.w};
            float bb[4] = {b4.x, b4.y, b4.z, b4.w};
            #pragma unroll
            for (int u = 0; u < 4; u++)
                #pragma unroll
                for (int v = 0; v < 4; v++)
                    acc[u][v] += aa[u] * bb[v];
        }
    }

    #pragma unroll
    for (int u = 0; u < 4; u++) {
        float4 o = make_float4(acc[u][0], acc[u][1], acc[u][2], acc[u][3]);
        *(float4*)&Cb[(long)(i0 + ty * 4 + u) * ldc + j0 + tx * 4] = o;
    }
}

// Per-batch iteration: r_{t+1} = r_t - (M_b r_t)/(L*P), acc = sum r_t.
// Then f[b][k] = inv_LP * sum_p G[b][k][p] * acc[p].
// One WG (256 threads) per batch; M_b (1MB) streamed from L2/L3 each step.
__global__ __launch_bounds__(256) void iterate_kernel(
    const float* __restrict__ M, const float* __restrict__ G,
    const float* __restrict__ y, float* __restrict__ f)
{
    const int b = blockIdx.x;
    __shared__ float r[P_];
    __shared__ float acc[P_];
    __shared__ float rn[P_];
    const int tid = threadIdx.x;
    const float inv_LP = 1.0f / ((float)L_ * (float)P_);

    const float* Mb = M + (long)b * P_ * P_;
    const float* Gb = G + (long)b * K_ * P_;

    for (int p = tid; p < P_; p += 256) { r[p] = y[b * P_ + p]; acc[p] = 0.f; }
    __syncthreads();

    const int row0 = tid >> 4;   // 16 rows in flight
    const int j    = tid & 15;   // 16 lanes per row

    for (int t = 0; t < L_; t++) {
        // acc += r (writes disjoint from matvec reads)
        for (int p = tid; p < P_; p += 256) acc[p] += r[p];
        // rn = r - inv_LP * M r
        for (int n = row0; n < P_; n += 16) {
            float s = 0.f;
            const float* Mr = Mb + (long)n * P_;
            for (int p = j; p < P_; p += 16) s += Mr[p] * r[p];
            s += __shfl_xor(s, 1);
            s += __shfl_xor(s, 2);
            s += __shfl_xor(s, 4);
            s += __shfl_xor(s, 8);
            if (j == 0) rn[n] = r[n] - s * inv_LP;
        }
        __syncthreads();
        for (int p = tid; p < P_; p += 256) r[p] = rn[p];
        __syncthreads();
    }

    // f[b][k] = inv_LP * sum_p G[b][k][p] * acc[p]; 4 lanes per k
    const int k = tid >> 2, jj = tid & 3;
    float s = 0.f;
    for (int p = jj; p < P_; p += 4) s += Gb[k * P_ + p] * acc[p];
    s += __shfl_xor(s, 1);
    s += __shfl_xor(s, 2);
    if (jj == 0) f[b * K_ + k] = s * inv_LP;
}

extern "C" void kernel_launch(void* const* d_in, const int* in_sizes, int n_in,
                              void* d_out, int out_size, void* d_ws, size_t ws_size,
                              hipStream_t stream) {
    const float* X     = (const float*)d_in[0];  // (B,D,P)
    const float* Xq    = (const float*)d_in[1];  // (B,D,K)
    const float* y     = (const float*)d_in[2];  // (B,P)
    const float* F     = (const float*)d_in[3];  // (D,D)
    const float* gamma = (const float*)d_in[4];  // (D)
    // d_in[5] = L (24), hardcoded
    float* out = (float*)d_out;                  // (B,K)

    float* ws = (float*)d_ws;
    float* W = ws;                                   // D*D        = 1,048,576 f
    float* Y = W + (long)D_ * D_;                    // B*D*P      = 33,554,432 f
    float* M = Y + (long)B_ * D_ * P_;               // B*P*P      = 16,777,216 f
    float* G = M + (long)B_ * P_ * P_;               // B*K*P      =  2,097,152 f

    // W = F^T diag(gamma) F   (D x D), symmetric
    gemm_tn<<<dim3(D_ / 64, D_ / 64, 1), 256, 0, stream>>>(
        F, D_, 0, F, D_, 0, W, D_, 0, D_, gamma);

    // Y_b = W X_b : Y[i][p] = sum_j W[j][i] X[b][j][p]  (uses W symmetric)
    gemm_tn<<<dim3(P_ / 64, D_ / 64, B_), 256, 0, stream>>>(
        W, D_, 0, X, P_, (long)D_ * P_, Y, P_, (long)D_ * P_, D_, nullptr);

    // M_b = X_b^T Y_b  (P x P)
    gemm_tn<<<dim3(P_ / 64, P_ / 64, B_), 256, 0, stream>>>(
        X, P_, (long)D_ * P_, Y, P_, (long)D_ * P_, M, P_, (long)P_ * P_, D_, nullptr);

    // G_b = Xq_b^T Y_b  (K x P)
    gemm_tn<<<dim3(P_ / 64, K_ / 64, B_), 256, 0, stream>>>(
        Xq, K_, (long)D_ * K_, Y, P_, (long)D_ * P_, G, P_, (long)K_ * P_, D_, nullptr);

    // 24-step iteration + final f, one WG per batch
    iterate_kernel<<<dim3(B_), 256, 0, stream>>>(M, G, y, out);
}

// Round 2
// 1723.300 us; speedup vs baseline: 3.7698x; 3.7698x over previous
//
#include <hip/hip_runtime.h>

// Problem constants (from reference): B=64, D=1024, P=512, K=64, L=24
#define B_ 64
#define D_ 1024
#define P_ 512
#define K_ 64
#define L_ 24

// Generic TN GEMM: C[m][n] = sum_k A[k][m] * (scale?scale[k]:1) * B[k][n]
// 64x64 tile per WG, 256 threads, 4x4 microtile, K-step 16 staged in LDS.
__global__ __launch_bounds__(256) void gemm_tn(
    const float* __restrict__ A, int lda, long sA,
    const float* __restrict__ B, int ldb, long sB,
    float* __restrict__ C, int ldc, long sC,
    int Kd, const float* __restrict__ scale)
{
    const float* Ab = A + (long)blockIdx.z * sA;
    const float* Bb = B + (long)blockIdx.z * sB;
    float*       Cb = C + (long)blockIdx.z * sC;
    const int i0 = blockIdx.y * 64;
    const int j0 = blockIdx.x * 64;

    __shared__ float As[16][64];
    __shared__ float Bs[16][64];

    const int tid = threadIdx.x;           // 0..255
    const int tx = tid & 15, ty = tid >> 4;
    const int ld = tid >> 4;               // k-row within tile (0..15)
    const int lc = (tid & 15) * 4;         // col within tile (float4)

    float acc[4][4] = {};

    for (int k0 = 0; k0 < Kd; k0 += 16) {
        float4 av = *(const float4*)&Ab[(long)(k0 + ld) * lda + i0 + lc];
        float4 bv = *(const float4*)&Bb[(long)(k0 + ld) * ldb + j0 + lc];
        if (scale) {
            float s = scale[k0 + ld];
            bv.x *= s; bv.y *= s; bv.z *= s; bv.w *= s;
        }
        __syncthreads();   // previous iteration's LDS reads complete
        *(float4*)&As[ld][lc] = av;
        *(float4*)&Bs[ld][lc] = bv;
        __syncthreads();
        #pragma unroll
        for (int kk = 0; kk < 16; kk++) {
            float4 a4 = *(const float4*)&As[kk][ty * 4];
            float4 b4 = *(const float4*)&Bs[kk][tx * 4];
            float aa[4] = {a4.x, a4.y, a4.z, a4.w};
            float bb[4] = {b4.x, b4.y, b4.z, b4.w};
            #pragma unroll
            for (int u = 0; u < 4; u++)
                #pragma unroll
                for (int v = 0; v < 4; v++)
                    acc[u][v] += aa[u] * bb[v];
        }
    }

    #pragma unroll
    for (int u = 0; u < 4; u++) {
        float4 o = make_float4(acc[u][0], acc[u][1], acc[u][2], acc[u][3]);
        *(float4*)&Cb[(long)(i0 + ty * 4 + u) * ldc + j0 + tx * 4] = o;
    }
}

// r = y; acc = 0
__global__ __launch_bounds__(256) void init_kernel(
    const float* __restrict__ y, float* __restrict__ r, float* __restrict__ acc)
{
    const int i = blockIdx.x * 256 + threadIdx.x;   // B*P total
    r[i] = y[i];
    acc[i] = 0.f;
}

// One time-step, parallel over (batch, 64-row slice):
//   acc[slice] += r;   r_next[slice] = r[slice] - inv_LP * (M r)[slice]
// Grid: (P/64, B). r staged in LDS; M rows read coalesced as float4.
__global__ __launch_bounds__(256) void step_kernel(
    const float* __restrict__ M, const float* __restrict__ r_cur,
    float* __restrict__ r_next, float* __restrict__ acc)
{
    const int b = blockIdx.y;
    const int slice = blockIdx.x;          // rows [slice*64, slice*64+64)
    const int tid = threadIdx.x;
    const float inv_LP = 1.0f / ((float)L_ * (float)P_);

    __shared__ float rs[P_];
    for (int p = tid; p < P_; p += 256) rs[p] = r_cur[b * P_ + p];
    __syncthreads();

    if (tid < 64) {
        const int p = slice * 64 + tid;
        acc[b * P_ + p] += rs[p];
    }

    const int j = tid & 15;                // 16 lanes per row
    #pragma unroll
    for (int pp = 0; pp < 4; pp++) {
        const int row = slice * 64 + pp * 16 + (tid >> 4);
        const float* Mr = M + ((long)b * P_ + row) * P_;
        float s = 0.f;
        #pragma unroll
        for (int i = 0; i < 8; i++) {
            const int c = i * 64 + 4 * j;
            float4 m4 = *(const float4*)&Mr[c];
            s += m4.x * rs[c] + m4.y * rs[c + 1] + m4.z * rs[c + 2] + m4.w * rs[c + 3];
        }
        s += __shfl_xor(s, 1);
        s += __shfl_xor(s, 2);
        s += __shfl_xor(s, 4);
        s += __shfl_xor(s, 8);
        if (j == 0) r_next[b * P_ + row] = rs[row] - s * inv_LP;
    }
}

// f[b][k] = inv_LP * sum_p G[b][k][p] * acc[b][p]
__global__ __launch_bounds__(256) void final_kernel(
    const float* __restrict__ G, const float* __restrict__ acc, float* __restrict__ f)
{
    const int b = blockIdx.x;
    const int tid = threadIdx.x;
    const float inv_LP = 1.0f / ((float)L_ * (float)P_);

    __shared__ float as[P_];
    for (int p = tid; p < P_; p += 256) as[p] = acc[b * P_ + p];
    __syncthreads();

    const int k = tid >> 2, jj = tid & 3;
    const float* Gb = G + (long)b * K_ * P_;
    float s = 0.f;
    for (int p = jj; p < P_; p += 4) s += Gb[k * P_ + p] * as[p];
    s += __shfl_xor(s, 1);
    s += __shfl_xor(s, 2);
    if (jj == 0) f[b * K_ + k] = s * inv_LP;
}

extern "C" void kernel_launch(void* const* d_in, const int* in_sizes, int n_in,
                              void* d_out, int out_size, void* d_ws, size_t ws_size,
                              hipStream_t stream) {
    const float* X     = (const float*)d_in[0];  // (B,D,P)
    const float* Xq    = (const float*)d_in[1];  // (B,D,K)
    const float* y     = (const float*)d_in[2];  // (B,P)
    const float* F     = (const float*)d_in[3];  // (D,D)
    const float* gamma = (const float*)d_in[4];  // (D)
    float* out = (float*)d_out;                  // (B,K)

    float* ws = (float*)d_ws;
    float* W  = ws;                                  // D*D
    float* Y  = W + (long)D_ * D_;                   // B*D*P
    float* M  = Y + (long)B_ * D_ * P_;              // B*P*P
    float* G  = M + (long)B_ * P_ * P_;              // B*K*P
    float* r0 = G + (long)B_ * K_ * P_;              // B*P
    float* r1 = r0 + (long)B_ * P_;                  // B*P
    float* ac = r1 + (long)B_ * P_;                  // B*P

    // W = F^T diag(gamma) F   (D x D), symmetric
    gemm_tn<<<dim3(D_ / 64, D_ / 64, 1), 256, 0, stream>>>(
        F, D_, 0, F, D_, 0, W, D_, 0, D_, gamma);

    // Y_b = W X_b (uses W symmetric): Y[i][p] = sum_j W[j][i] X[b][j][p]
    gemm_tn<<<dim3(P_ / 64, D_ / 64, B_), 256, 0, stream>>>(
        W, D_, 0, X, P_, (long)D_ * P_, Y, P_, (long)D_ * P_, D_, nullptr);

    // M_b = X_b^T Y_b  (P x P)
    gemm_tn<<<dim3(P_ / 64, P_ / 64, B_), 256, 0, stream>>>(
        X, P_, (long)D_ * P_, Y, P_, (long)D_ * P_, M, P_, (long)P_ * P_, D_, nullptr);

    // G_b = Xq_b^T Y_b  (K x P)
    gemm_tn<<<dim3(P_ / 64, K_ / 64, B_), 256, 0, stream>>>(
        Xq, K_, (long)D_ * K_, Y, P_, (long)D_ * P_, G, P_, (long)K_ * P_, D_, nullptr);

    // Iteration: 24 parallel step kernels (ping-pong r buffers)
    init_kernel<<<dim3(B_ * P_ / 256), 256, 0, stream>>>(y, r0, ac);
    float* rc = r0; float* rn = r1;
    for (int t = 0; t < L_; t++) {
        step_kernel<<<dim3(P_ / 64, B_), 256, 0, stream>>>(M, rc, rn, ac);
        float* tmp = rc; rc = rn; rn = tmp;
    }

    final_kernel<<<dim3(B_), 256, 0, stream>>>(G, ac, out);
}

// Round 3
// 462.124 us; speedup vs baseline: 14.0579x; 3.7291x over previous
//
#include <hip/hip_runtime.h>

// Problem constants: B=64, D=1024, P=512, K=64, L=24
#define B_ 64
#define D_ 1024
#define P_ 512
#define K_ 64
#define L_ 24

typedef unsigned int uint;
typedef unsigned short ushort;
typedef __attribute__((ext_vector_type(8))) short short8;    // 8 bf16 (4 VGPRs) MFMA frag
typedef __attribute__((ext_vector_type(8))) ushort ushort8;
typedef __attribute__((ext_vector_type(4))) ushort ushort4_t;
typedef __attribute__((ext_vector_type(4))) float f32x4;

__device__ inline ushort f2bf(float f) {                     // fp32 -> bf16 RNE
    uint u = __float_as_uint(f);
    u = (u + 0x7FFFu + ((u >> 16) & 1u)) >> 16;
    return (ushort)u;
}
__device__ inline float bf2f(ushort u) { return __uint_as_float((uint)u << 16); }

#define GLOBAL_LOAD_LDS16(g, l) __builtin_amdgcn_global_load_lds( \
    (const __attribute__((address_space(1))) void*)(g),           \
    (__attribute__((address_space(3))) void*)(l), 16, 0, 0)

// ---------------- fp32 TN GEMM (kept for W = F^T diag(gamma) F only) --------
__global__ __launch_bounds__(256) void gemm_tn(
    const float* __restrict__ A, int lda, long sA,
    const float* __restrict__ B, int ldb, long sB,
    float* __restrict__ C, int ldc, long sC,
    int Kd, const float* __restrict__ scale)
{
    const float* Ab = A + (long)blockIdx.z * sA;
    const float* Bb = B + (long)blockIdx.z * sB;
    float*       Cb = C + (long)blockIdx.z * sC;
    const int i0 = blockIdx.y * 64;
    const int j0 = blockIdx.x * 64;

    __shared__ float As[16][64];
    __shared__ float Bs[16][64];

    const int tid = threadIdx.x;
    const int tx = tid & 15, ty = tid >> 4;
    const int ld = tid >> 4;
    const int lc = (tid & 15) * 4;

    float acc[4][4] = {};

    for (int k0 = 0; k0 < Kd; k0 += 16) {
        float4 av = *(const float4*)&Ab[(long)(k0 + ld) * lda + i0 + lc];
        float4 bv = *(const float4*)&Bb[(long)(k0 + ld) * ldb + j0 + lc];
        if (scale) {
            float s = scale[k0 + ld];
            bv.x *= s; bv.y *= s; bv.z *= s; bv.w *= s;
        }
        __syncthreads();
        *(float4*)&As[ld][lc] = av;
        *(float4*)&Bs[ld][lc] = bv;
        __syncthreads();
        #pragma unroll
        for (int kk = 0; kk < 16; kk++) {
            float4 a4 = *(const float4*)&As[kk][ty * 4];
            float4 b4 = *(const float4*)&Bs[kk][tx * 4];
            float aa[4] = {a4.x, a4.y, a4.z, a4.w};
            float bb[4] = {b4.x, b4.y, b4.z, b4.w};
            #pragma unroll
            for (int u = 0; u < 4; u++)
                #pragma unroll
                for (int v = 0; v < 4; v++)
                    acc[u][v] += aa[u] * bb[v];
        }
    }
    #pragma unroll
    for (int u = 0; u < 4; u++) {
        float4 o = make_float4(acc[u][0], acc[u][1], acc[u][2], acc[u][3]);
        *(float4*)&Cb[(long)(i0 + ty * 4 + u) * ldc + j0 + tx * 4] = o;
    }
}

// ---------------- fp32 -> bf16 elementwise (for W, symmetric: no transpose) -
__global__ __launch_bounds__(256) void convert_bf16(
    const float* __restrict__ in, ushort* __restrict__ out)
{
    const int i = (blockIdx.x * 256 + threadIdx.x) * 4;
    float4 v = *(const float4*)&in[i];
    ushort4_t o = {f2bf(v.x), f2bf(v.y), f2bf(v.z), f2bf(v.w)};
    *(ushort4_t*)&out[i] = o;
}

// ---------------- tiled transpose + convert: in (z,R,C) fp32 -> out (z,C,R) bf16
__global__ __launch_bounds__(256) void transpose_convert(
    const float* __restrict__ in, ushort* __restrict__ out, int R, int Cc)
{
    __shared__ float t[64][65];
    const int c0 = blockIdx.x * 64, r0 = blockIdx.y * 64;
    const float* ib = in + (size_t)blockIdx.z * R * Cc;
    ushort* ob = out + (size_t)blockIdx.z * R * Cc;
    const int cc = threadIdx.x & 63, rr = threadIdx.x >> 6;
    #pragma unroll
    for (int i = 0; i < 16; i++)
        t[rr + 4 * i][cc] = ib[(size_t)(r0 + rr + 4 * i) * Cc + c0 + cc];
    __syncthreads();
    #pragma unroll
    for (int i = 0; i < 16; i++)
        ob[(size_t)(c0 + rr + 4 * i) * R + r0 + cc] = f2bf(t[cc][rr + 4 * i]);
}

// ---------------- bf16 MFMA GEMM, both operands M-major [M][Kd] (K contiguous)
// C[m][n] = sum_k A[m][k] * B[n][k].
// OUT_MODE 0: fp32 C[m][n] (ldc); OUT_MODE 1: bf16 transposed out[n][m] (ldc).
// 256 thds = 4 waves (2x2), tile BM x BN, K-step 64, XOR-swizzled LDS,
// global_load_lds with pre-swizzled source (involution both sides).
template<int BM, int BN, int OUT_MODE>
__global__ __launch_bounds__(256) void mfma_tn(
    const ushort* __restrict__ A, long sA,
    const ushort* __restrict__ Bm, long sB,
    void* __restrict__ C, long sC, int ldc, int Kd)
{
    constexpr int FM = BM / 32;   // 16x16 frags per wave along M
    constexpr int FN = BN / 32;
    __shared__ ushort As[BM * 64];
    __shared__ ushort Bs[BN * 64];

    const int tid = threadIdx.x;
    const int lane = tid & 63;
    const int w = tid >> 6;
    const int wm0 = (w >> 1) * (BM / 2);
    const int wn0 = (w & 1) * (BN / 2);
    const int m0 = blockIdx.y * BM;
    const int n0 = blockIdx.x * BN;
    const int z = blockIdx.z;

    const ushort* Ab = A + (size_t)z * sA + (size_t)m0 * Kd;
    const ushort* Bb = Bm + (size_t)z * sB + (size_t)n0 * Kd;

    f32x4 acc[FM][FN] = {};

    const int srow = lane >> 3;      // row within 8-row staging group
    const int schunk = lane & 7;     // dest 16B chunk within 128B row

    for (int k0 = 0; k0 < Kd; k0 += 64) {
        #pragma unroll
        for (int q = 0; q < BM / 32; q++) {
            int qq = w * (BM / 32) + q;
            int m = qq * 8 + srow;
            int cs = schunk ^ (m & 7);
            GLOBAL_LOAD_LDS16(Ab + (size_t)m * Kd + k0 + cs * 8, &As[qq * 512]);
        }
        #pragma unroll
        for (int q = 0; q < BN / 32; q++) {
            int qq = w * (BN / 32) + q;
            int m = qq * 8 + srow;
            int cs = schunk ^ (m & 7);
            GLOBAL_LOAD_LDS16(Bb + (size_t)m * Kd + k0 + cs * 8, &Bs[qq * 512]);
        }
        __syncthreads();

        short8 af[FM][2], bfr[FN][2];
        #pragma unroll
        for (int i = 0; i < FM; i++) {
            int ml = wm0 + 16 * i + (lane & 15);
            #pragma unroll
            for (int h = 0; h < 2; h++) {
                int c = (h * 4 + (lane >> 4)) ^ (ml & 7);
                af[i][h] = *(const short8*)&As[ml * 64 + c * 8];
            }
        }
        #pragma unroll
        for (int j = 0; j < FN; j++) {
            int nl = wn0 + 16 * j + (lane & 15);
            #pragma unroll
            for (int h = 0; h < 2; h++) {
                int c = (h * 4 + (lane >> 4)) ^ (nl & 7);
                bfr[j][h] = *(const short8*)&Bs[nl * 64 + c * 8];
            }
        }
        #pragma unroll
        for (int i = 0; i < FM; i++)
            #pragma unroll
            for (int j = 0; j < FN; j++) {
                acc[i][j] = __builtin_amdgcn_mfma_f32_16x16x32_bf16(af[i][0], bfr[j][0], acc[i][j], 0, 0, 0);
                acc[i][j] = __builtin_amdgcn_mfma_f32_16x16x32_bf16(af[i][1], bfr[j][1], acc[i][j], 0, 0, 0);
            }
        __syncthreads();
    }

    if (OUT_MODE == 0) {
        float* Cb = (float*)C + (size_t)z * sC;
        #pragma unroll
        for (int i = 0; i < FM; i++)
            #pragma unroll
            for (int j = 0; j < FN; j++) {
                int row0 = m0 + wm0 + 16 * i + 4 * (lane >> 4);
                int col = n0 + wn0 + 16 * j + (lane & 15);
                #pragma unroll
                for (int r = 0; r < 4; r++)
                    Cb[(size_t)(row0 + r) * ldc + col] = acc[i][j][r];
            }
    } else {
        ushort* Cb = (ushort*)C + (size_t)z * sC;
        #pragma unroll
        for (int i = 0; i < FM; i++)
            #pragma unroll
            for (int j = 0; j < FN; j++) {
                int nn = n0 + wn0 + 16 * j + (lane & 15);
                int mm = m0 + wm0 + 16 * i + 4 * (lane >> 4);
                ushort4_t o = {f2bf(acc[i][j][0]), f2bf(acc[i][j][1]),
                               f2bf(acc[i][j][2]), f2bf(acc[i][j][3])};
                *(ushort4_t*)&Cb[(size_t)nn * ldc + mm] = o;
            }
    }
}

// ---------------- iteration ------------------------------------------------
__global__ __launch_bounds__(256) void init_kernel(
    const float* __restrict__ y, float* __restrict__ r, float* __restrict__ acc)
{
    const int i = blockIdx.x * 256 + threadIdx.x;
    r[i] = y[i];
    acc[i] = 0.f;
}

// One step: acc[slice] += r; r_next[slice] = r[slice] - inv_LP * (M r)[slice]
// M is bf16 (symmetric, stored either orientation). Grid (P/64, B).
__global__ __launch_bounds__(256) void step_kernel(
    const ushort* __restrict__ M, const float* __restrict__ r_cur,
    float* __restrict__ r_next, float* __restrict__ acc)
{
    const int b = blockIdx.y;
    const int slice = blockIdx.x;
    const int tid = threadIdx.x;
    const float inv_LP = 1.0f / ((float)L_ * (float)P_);

    __shared__ float rs[P_];
    for (int p = tid; p < P_; p += 256) rs[p] = r_cur[b * P_ + p];
    __syncthreads();

    if (tid < 64) {
        const int p = slice * 64 + tid;
        acc[b * P_ + p] += rs[p];
    }

    const int j = tid & 15;
    #pragma unroll
    for (int pp = 0; pp < 4; pp++) {
        const int row = slice * 64 + pp * 16 + (tid >> 4);
        const ushort* Mr = M + ((size_t)b * P_ + row) * P_;
        float s = 0.f;
        #pragma unroll
        for (int i = 0; i < 4; i++) {
            const int c = i * 128 + 8 * j;
            ushort8 m8 = *(const ushort8*)&Mr[c];
            s += bf2f(m8[0]) * rs[c]     + bf2f(m8[1]) * rs[c + 1]
               + bf2f(m8[2]) * rs[c + 2] + bf2f(m8[3]) * rs[c + 3]
               + bf2f(m8[4]) * rs[c + 4] + bf2f(m8[5]) * rs[c + 5]
               + bf2f(m8[6]) * rs[c + 6] + bf2f(m8[7]) * rs[c + 7];
        }
        s += __shfl_xor(s, 1);
        s += __shfl_xor(s, 2);
        s += __shfl_xor(s, 4);
        s += __shfl_xor(s, 8);
        if (j == 0) r_next[b * P_ + row] = rs[row] - s * inv_LP;
    }
}

// f[b][k] = inv_LP * sum_p G[b][k][p] * acc[b][p]
__global__ __launch_bounds__(256) void final_kernel(
    const float* __restrict__ G, const float* __restrict__ acc, float* __restrict__ f)
{
    const int b = blockIdx.x;
    const int tid = threadIdx.x;
    const float inv_LP = 1.0f / ((float)L_ * (float)P_);

    __shared__ float as[P_];
    for (int p = tid; p < P_; p += 256) as[p] = acc[b * P_ + p];
    __syncthreads();

    const int k = tid >> 2, jj = tid & 3;
    const float* Gb = G + (size_t)b * K_ * P_;
    float s = 0.f;
    for (int p = jj; p < P_; p += 4) s += Gb[k * P_ + p] * as[p];
    s += __shfl_xor(s, 1);
    s += __shfl_xor(s, 2);
    if (jj == 0) f[b * K_ + k] = s * inv_LP;
}

extern "C" void kernel_launch(void* const* d_in, const int* in_sizes, int n_in,
                              void* d_out, int out_size, void* d_ws, size_t ws_size,
                              hipStream_t stream) {
    const float* X     = (const float*)d_in[0];  // (B,D,P)
    const float* Xq    = (const float*)d_in[1];  // (B,D,K)
    const float* y     = (const float*)d_in[2];  // (B,P)
    const float* F     = (const float*)d_in[3];  // (D,D)
    const float* gamma = (const float*)d_in[4];  // (D)
    float* out = (float*)d_out;                  // (B,K)

    float* ws = (float*)d_ws;
    float* W  = ws;                                   // D*D fp32
    float* G  = W + (size_t)D_ * D_;                  // B*K*P fp32
    float* r0 = G + (size_t)B_ * K_ * P_;             // B*P
    float* r1 = r0 + (size_t)B_ * P_;                 // B*P
    float* ac = r1 + (size_t)B_ * P_;                 // B*P
    ushort* Wb  = (ushort*)(ac + (size_t)B_ * P_);    // D*D bf16 (symmetric)
    ushort* Xt  = Wb + (size_t)D_ * D_;               // (B,P,D) bf16
    ushort* Xqt = Xt + (size_t)B_ * P_ * D_;          // (B,K,D) bf16
    ushort* Yt  = Xqt + (size_t)B_ * K_ * D_;         // (B,P,D) bf16
    ushort* Mb  = Yt + (size_t)B_ * P_ * D_;          // (B,P,P) bf16 (symmetric)

    // W = F^T diag(gamma) F  (fp32, symmetric), then bf16 copy
    gemm_tn<<<dim3(D_ / 64, D_ / 64, 1), 256, 0, stream>>>(
        F, D_, 0, F, D_, 0, W, D_, 0, D_, gamma);
    convert_bf16<<<dim3(D_ * D_ / 1024), 256, 0, stream>>>(W, Wb);

    // Transposed bf16 operands: Xt[b][p][d], Xqt[b][k][d]
    transpose_convert<<<dim3(P_ / 64, D_ / 64, B_), 256, 0, stream>>>(X, Xt, D_, P_);
    transpose_convert<<<dim3(K_ / 64, D_ / 64, B_), 256, 0, stream>>>(Xq, Xqt, D_, K_);

    // Yt[b][p][d] = (W X_b)^T : A=Wb [d][j], B=Xt [p][j], transposed bf16 store
    mfma_tn<128, 128, 1><<<dim3(P_ / 128, D_ / 128, B_), 256, 0, stream>>>(
        Wb, 0, Xt, (long)P_ * D_, Yt, (long)P_ * D_, D_, D_);

    // Mb[b][p][q] = M_b^T (= M_b, symmetric): A=Xt [q][d], B=Yt [p][d]
    mfma_tn<128, 128, 1><<<dim3(P_ / 128, P_ / 128, B_), 256, 0, stream>>>(
        Xt, (long)P_ * D_, Yt, (long)P_ * D_, Mb, (long)P_ * P_, P_, D_);

    // G[b][k][p] fp32: A=Xqt [k][d], B=Yt [p][d]
    mfma_tn<64, 128, 0><<<dim3(P_ / 128, K_ / 64, B_), 256, 0, stream>>>(
        Xqt, (long)K_ * D_, Yt, (long)P_ * D_, G, (long)K_ * P_, P_, D_);

    // Iteration: 24 parallel step kernels (ping-pong r buffers)
    init_kernel<<<dim3(B_ * P_ / 256), 256, 0, stream>>>(y, r0, ac);
    float* rc = r0; float* rn = r1;
    for (int t = 0; t < L_; t++) {
        step_kernel<<<dim3(P_ / 64, B_), 256, 0, stream>>>(Mb, rc, rn, ac);
        float* tmp = rc; rc = rn; rn = tmp;
    }

    final_kernel<<<dim3(B_), 256, 0, stream>>>(G, ac, out);
}

// Round 5
// 376.535 us; speedup vs baseline: 17.2533x; 1.2273x over previous
//
#include <hip/hip_runtime.h>

// Problem constants: B=64, D=1024, P=512, K=64, L=24
#define B_ 64
#define D_ 1024
#define P_ 512
#define K_ 64
#define L_ 24

typedef unsigned int uint;
typedef unsigned short ushort;
typedef __attribute__((ext_vector_type(8))) short short8;    // 8 bf16 MFMA frag
typedef __attribute__((ext_vector_type(8))) ushort ushort8;
typedef __attribute__((ext_vector_type(4))) ushort ushort4_t;
typedef __attribute__((ext_vector_type(4))) float f32x4;

__device__ inline ushort f2bf(float f) {                     // fp32 -> bf16 RNE
    uint u = __float_as_uint(f);
    u = (u + 0x7FFFu + ((u >> 16) & 1u)) >> 16;
    return (ushort)u;
}
__device__ inline float bf2f(ushort u) { return __uint_as_float((uint)u << 16); }

#define GLOBAL_LOAD_LDS16(g, l) __builtin_amdgcn_global_load_lds( \
    (const __attribute__((address_space(1))) void*)(g),           \
    (__attribute__((address_space(3))) void*)(l), 16, 0, 0)

// ---- tiled transpose + convert (+optional input-row scale):
// in (z,R,C) fp32 -> out (z,C,R) bf16 ; out[c][r] = scale[r] * in[r][c]
__global__ __launch_bounds__(256) void transpose_convert(
    const float* __restrict__ in, ushort* __restrict__ out, int R, int Cc,
    const float* __restrict__ scale)
{
    __shared__ float t[64][65];
    const int c0 = blockIdx.x * 64, r0 = blockIdx.y * 64;
    const float* ib = in + (size_t)blockIdx.z * R * Cc;
    ushort* ob = out + (size_t)blockIdx.z * R * Cc;
    const int cc = threadIdx.x & 63, rr = threadIdx.x >> 6;
    #pragma unroll
    for (int i = 0; i < 16; i++)
        t[rr + 4 * i][cc] = ib[(size_t)(r0 + rr + 4 * i) * Cc + c0 + cc];
    __syncthreads();
    const float sc = scale ? scale[r0 + cc] : 1.0f;
    #pragma unroll
    for (int i = 0; i < 16; i++)
        ob[(size_t)(c0 + rr + 4 * i) * R + r0 + cc] = f2bf(sc * t[cc][rr + 4 * i]);
}

// ---- bf16 MFMA GEMM, operands M-major [M][Kd] (K contiguous):
// C[m][n] = sum_k A[m][k] * B[n][k].
// OUT_MODE 0: fp32 C[m][n]; OUT_MODE 1: bf16 transposed out[n][m].
template<int BM, int BN, int OUT_MODE>
__global__ __launch_bounds__(256) void mfma_tn(
    const ushort* __restrict__ A, long sA,
    const ushort* __restrict__ Bm, long sB,
    void* __restrict__ C, long sC, int ldc, int Kd)
{
    constexpr int FM = BM / 32;
    constexpr int FN = BN / 32;
    __shared__ ushort As[BM * 64];
    __shared__ ushort Bs[BN * 64];

    const int tid = threadIdx.x;
    const int lane = tid & 63;
    const int w = tid >> 6;
    const int wm0 = (w >> 1) * (BM / 2);
    const int wn0 = (w & 1) * (BN / 2);
    const int m0 = blockIdx.y * BM;
    const int n0 = blockIdx.x * BN;
    const int z = blockIdx.z;

    const ushort* Ab = A + (size_t)z * sA + (size_t)m0 * Kd;
    const ushort* Bb = Bm + (size_t)z * sB + (size_t)n0 * Kd;

    f32x4 acc[FM][FN] = {};

    const int srow = lane >> 3;
    const int schunk = lane & 7;

    for (int k0 = 0; k0 < Kd; k0 += 64) {
        #pragma unroll
        for (int q = 0; q < BM / 32; q++) {
            int qq = w * (BM / 32) + q;
            int m = qq * 8 + srow;
            int cs = schunk ^ (m & 7);
            GLOBAL_LOAD_LDS16(Ab + (size_t)m * Kd + k0 + cs * 8, &As[qq * 512]);
        }
        #pragma unroll
        for (int q = 0; q < BN / 32; q++) {
            int qq = w * (BN / 32) + q;
            int m = qq * 8 + srow;
            int cs = schunk ^ (m & 7);
            GLOBAL_LOAD_LDS16(Bb + (size_t)m * Kd + k0 + cs * 8, &Bs[qq * 512]);
        }
        __syncthreads();

        short8 af[FM][2], bfr[FN][2];
        #pragma unroll
        for (int i = 0; i < FM; i++) {
            int ml = wm0 + 16 * i + (lane & 15);
            #pragma unroll
            for (int h = 0; h < 2; h++) {
                int c = (h * 4 + (lane >> 4)) ^ (ml & 7);
                af[i][h] = *(const short8*)&As[ml * 64 + c * 8];
            }
        }
        #pragma unroll
        for (int j = 0; j < FN; j++) {
            int nl = wn0 + 16 * j + (lane & 15);
            #pragma unroll
            for (int h = 0; h < 2; h++) {
                int c = (h * 4 + (lane >> 4)) ^ (nl & 7);
                bfr[j][h] = *(const short8*)&Bs[nl * 64 + c * 8];
            }
        }
        #pragma unroll
        for (int i = 0; i < FM; i++)
            #pragma unroll
            for (int j = 0; j < FN; j++) {
                acc[i][j] = __builtin_amdgcn_mfma_f32_16x16x32_bf16(af[i][0], bfr[j][0], acc[i][j], 0, 0, 0);
                acc[i][j] = __builtin_amdgcn_mfma_f32_16x16x32_bf16(af[i][1], bfr[j][1], acc[i][j], 0, 0, 0);
            }
        __syncthreads();
    }

    if (OUT_MODE == 0) {
        float* Cb = (float*)C + (size_t)z * sC;
        #pragma unroll
        for (int i = 0; i < FM; i++)
            #pragma unroll
            for (int j = 0; j < FN; j++) {
                int row0 = m0 + wm0 + 16 * i + 4 * (lane >> 4);
                int col = n0 + wn0 + 16 * j + (lane & 15);
                #pragma unroll
                for (int r = 0; r < 4; r++)
                    Cb[(size_t)(row0 + r) * ldc + col] = acc[i][j][r];
            }
    } else {
        ushort* Cb = (ushort*)C + (size_t)z * sC;
        #pragma unroll
        for (int i = 0; i < FM; i++)
            #pragma unroll
            for (int j = 0; j < FN; j++) {
                int nn = n0 + wn0 + 16 * j + (lane & 15);
                int mm = m0 + wm0 + 16 * i + 4 * (lane >> 4);
                ushort4_t o = {f2bf(acc[i][j][0]), f2bf(acc[i][j][1]),
                               f2bf(acc[i][j][2]), f2bf(acc[i][j][3])};
                *(ushort4_t*)&Cb[(size_t)nn * ldc + mm] = o;
            }
    }
}

// ---- iteration --------------------------------------------------------------
__global__ __launch_bounds__(256) void init_kernel(
    const float* __restrict__ y, float* __restrict__ r, float* __restrict__ acc)
{
    const int i = blockIdx.x * 256 + threadIdx.x;
    r[i] = y[i];
    acc[i] = 0.f;
}

// One step: acc[rows] += r; r_next[rows] = r[rows] - inv_LP * (M r)[rows]
// Grid (P/16, B): 2048 WGs, 16 rows each, 16 lanes per row (full occupancy).
__global__ __launch_bounds__(256) void step_kernel(
    const ushort* __restrict__ M, const float* __restrict__ r_cur,
    float* __restrict__ r_next, float* __restrict__ acc)
{
    const int b = blockIdx.y;
    const int slice = blockIdx.x;          // rows [slice*16, slice*16+16)
    const int tid = threadIdx.x;
    const float inv_LP = 1.0f / ((float)L_ * (float)P_);

    __shared__ float rs[P_];
    for (int p = tid; p < P_; p += 256) rs[p] = r_cur[b * P_ + p];
    __syncthreads();

    const int row = slice * 16 + (tid >> 4);   // global row
    const int j = tid & 15;                    // 16 lanes per row

    const ushort* Mr = M + ((size_t)b * P_ + row) * P_;
    float s = 0.f;
    #pragma unroll
    for (int i = 0; i < 4; i++) {
        const int c = i * 128 + 8 * j;
        ushort8 m8 = *(const ushort8*)&Mr[c];
        s += bf2f(m8[0]) * rs[c]     + bf2f(m8[1]) * rs[c + 1]
           + bf2f(m8[2]) * rs[c + 2] + bf2f(m8[3]) * rs[c + 3]
           + bf2f(m8[4]) * rs[c + 4] + bf2f(m8[5]) * rs[c + 5]
           + bf2f(m8[6]) * rs[c + 6] + bf2f(m8[7]) * rs[c + 7];
    }
    s += __shfl_xor(s, 1);
    s += __shfl_xor(s, 2);
    s += __shfl_xor(s, 4);
    s += __shfl_xor(s, 8);
    if (j == 0) {
        acc[b * P_ + row] += rs[row];
        r_next[b * P_ + row] = rs[row] - s * inv_LP;
    }
}

// f[b][k] = inv_LP * sum_p G[b][k][p] * acc[b][p]
__global__ __launch_bounds__(256) void final_kernel(
    const float* __restrict__ G, const float* __restrict__ acc, float* __restrict__ f)
{
    const int b = blockIdx.x;
    const int tid = threadIdx.x;
    const float inv_LP = 1.0f / ((float)L_ * (float)P_);

    __shared__ float as[P_];
    for (int p = tid; p < P_; p += 256) as[p] = acc[b * P_ + p];
    __syncthreads();

    const int k = tid >> 2, jj = tid & 3;
    const float* Gb = G + (size_t)b * K_ * P_;
    float s = 0.f;
    for (int p = jj; p < P_; p += 4) s += Gb[k * P_ + p] * as[p];
    s += __shfl_xor(s, 1);
    s += __shfl_xor(s, 2);
    if (jj == 0) f[b * K_ + k] = s * inv_LP;
}

extern "C" void kernel_launch(void* const* d_in, const int* in_sizes, int n_in,
                              void* d_out, int out_size, void* d_ws, size_t ws_size,
                              hipStream_t stream) {
    const float* X     = (const float*)d_in[0];  // (B,D,P)
    const float* Xq    = (const float*)d_in[1];  // (B,D,K)
    const float* y     = (const float*)d_in[2];  // (B,P)
    const float* F     = (const float*)d_in[3];  // (D,D)
    const float* gamma = (const float*)d_in[4];  // (D)
    float* out = (float*)d_out;                  // (B,K)

    float* ws = (float*)d_ws;
    float* G  = ws;                                   // B*K*P fp32
    float* r0 = G + (size_t)B_ * K_ * P_;             // B*P
    float* r1 = r0 + (size_t)B_ * P_;                 // B*P
    float* ac = r1 + (size_t)B_ * P_;                 // B*P
    ushort* Wb  = (ushort*)(ac + (size_t)B_ * P_);    // D*D bf16 (symmetric)
    ushort* Ft  = Wb + (size_t)D_ * D_;               // F^T bf16
    ushort* Fg  = Ft + (size_t)D_ * D_;               // gamma-scaled F^T bf16
    ushort* Xt  = Fg + (size_t)D_ * D_;               // (B,P,D) bf16
    ushort* Xqt = Xt + (size_t)B_ * P_ * D_;          // (B,K,D) bf16
    ushort* Yt  = Xqt + (size_t)B_ * K_ * D_;         // (B,P,D) bf16
    ushort* Mb  = Yt + (size_t)B_ * P_ * D_;          // (B,P,P) bf16 (symmetric)

    // Transposed bf16 operands
    transpose_convert<<<dim3(D_ / 64, D_ / 64, 1), 256, 0, stream>>>(F, Ft, D_, D_, nullptr);
    transpose_convert<<<dim3(D_ / 64, D_ / 64, 1), 256, 0, stream>>>(F, Fg, D_, D_, gamma);
    transpose_convert<<<dim3(P_ / 64, D_ / 64, B_), 256, 0, stream>>>(X, Xt, D_, P_, nullptr);
    transpose_convert<<<dim3(K_ / 64, D_ / 64, B_), 256, 0, stream>>>(Xq, Xqt, D_, K_, nullptr);

    // W[m][n] = sum_k gamma[k] F[k][m] F[k][n]  (bf16 out; symmetric)
    mfma_tn<128, 128, 1><<<dim3(D_ / 128, D_ / 128, 1), 256, 0, stream>>>(
        Fg, 0, Ft, 0, Wb, 0, D_, D_);

    // Yt[b][p][d] = (W X_b)^T
    mfma_tn<128, 128, 1><<<dim3(P_ / 128, D_ / 128, B_), 256, 0, stream>>>(
        Wb, 0, Xt, (long)P_ * D_, Yt, (long)P_ * D_, D_, D_);

    // Mb[b][p][q] = X_b^T Y_b (symmetric)
    mfma_tn<128, 128, 1><<<dim3(P_ / 128, P_ / 128, B_), 256, 0, stream>>>(
        Xt, (long)P_ * D_, Yt, (long)P_ * D_, Mb, (long)P_ * P_, P_, D_);

    // G[b][k][p] fp32
    mfma_tn<64, 128, 0><<<dim3(P_ / 128, K_ / 64, B_), 256, 0, stream>>>(
        Xqt, (long)K_ * D_, Yt, (long)P_ * D_, G, (long)K_ * P_, P_, D_);

    // Iteration: 24 parallel step kernels (ping-pong r buffers), 2048 WGs each
    init_kernel<<<dim3(B_ * P_ / 256), 256, 0, stream>>>(y, r0, ac);
    float* rc = r0; float* rn = r1;
    for (int t = 0; t < L_; t++) {
        step_kernel<<<dim3(P_ / 16, B_), 256, 0, stream>>>(Mb, rc, rn, ac);
        float* tmp = rc; rc = rn; rn = tmp;
    }

    final_kernel<<<dim3(B_), 256, 0, stream>>>(G, ac, out);
}

// Round 6
// 358.664 us; speedup vs baseline: 18.1130x; 1.0498x over previous
//
#include <hip/hip_runtime.h>

// Problem constants: B=64, D=1024, P=512, K=64, L=24
#define B_ 64
#define D_ 1024
#define P_ 512
#define K_ 64
#define L_ 24

typedef unsigned int uint;
typedef unsigned short ushort;
typedef __attribute__((ext_vector_type(8))) short short8;    // 8 bf16 MFMA frag
typedef __attribute__((ext_vector_type(8))) ushort ushort8;
typedef __attribute__((ext_vector_type(4))) ushort ushort4_t;
typedef __attribute__((ext_vector_type(4))) float f32x4;

__device__ inline ushort f2bf(float f) {                     // fp32 -> bf16 RNE
    uint u = __float_as_uint(f);
    u = (u + 0x7FFFu + ((u >> 16) & 1u)) >> 16;
    return (ushort)u;
}
__device__ inline float bf2f(ushort u) { return __uint_as_float((uint)u << 16); }

#define GLOBAL_LOAD_LDS16(g, l) __builtin_amdgcn_global_load_lds( \
    (const __attribute__((address_space(1))) void*)(g),           \
    (__attribute__((address_space(3))) void*)(l), 16, 0, 0)

// ---- tiled transpose + convert (+optional input-row scale):
// in (z,R,C) fp32 -> out (z,C,R) bf16 ; out[c][r] = scale[r] * in[r][c]
__global__ __launch_bounds__(256) void transpose_convert(
    const float* __restrict__ in, ushort* __restrict__ out, int R, int Cc,
    const float* __restrict__ scale)
{
    __shared__ float t[64][65];
    const int c0 = blockIdx.x * 64, r0 = blockIdx.y * 64;
    const float* ib = in + (size_t)blockIdx.z * R * Cc;
    ushort* ob = out + (size_t)blockIdx.z * R * Cc;
    const int cc = threadIdx.x & 63, rr = threadIdx.x >> 6;
    #pragma unroll
    for (int i = 0; i < 16; i++)
        t[rr + 4 * i][cc] = ib[(size_t)(r0 + rr + 4 * i) * Cc + c0 + cc];
    __syncthreads();
    const float sc = scale ? scale[r0 + cc] : 1.0f;
    #pragma unroll
    for (int i = 0; i < 16; i++)
        ob[(size_t)(c0 + rr + 4 * i) * R + r0 + cc] = f2bf(sc * t[cc][rr + 4 * i]);
}

// ---- bf16 MFMA GEMM, operands M-major [M][Kd] (K contiguous):
// C[m][n] = sum_k A[m][k] * B[n][k].
// OUT_MODE 0: fp32 C[m][n]; OUT_MODE 1: bf16 transposed out[n][m].
template<int BM, int BN, int OUT_MODE>
__global__ __launch_bounds__(256) void mfma_tn(
    const ushort* __restrict__ A, long sA,
    const ushort* __restrict__ Bm, long sB,
    void* __restrict__ C, long sC, int ldc, int Kd)
{
    constexpr int FM = BM / 32;
    constexpr int FN = BN / 32;
    __shared__ ushort As[BM * 64];
    __shared__ ushort Bs[BN * 64];

    const int tid = threadIdx.x;
    const int lane = tid & 63;
    const int w = tid >> 6;
    const int wm0 = (w >> 1) * (BM / 2);
    const int wn0 = (w & 1) * (BN / 2);
    const int m0 = blockIdx.y * BM;
    const int n0 = blockIdx.x * BN;
    const int z = blockIdx.z;

    const ushort* Ab = A + (size_t)z * sA + (size_t)m0 * Kd;
    const ushort* Bb = Bm + (size_t)z * sB + (size_t)n0 * Kd;

    f32x4 acc[FM][FN] = {};

    const int srow = lane >> 3;
    const int schunk = lane & 7;

    for (int k0 = 0; k0 < Kd; k0 += 64) {
        #pragma unroll
        for (int q = 0; q < BM / 32; q++) {
            int qq = w * (BM / 32) + q;
            int m = qq * 8 + srow;
            int cs = schunk ^ (m & 7);
            GLOBAL_LOAD_LDS16(Ab + (size_t)m * Kd + k0 + cs * 8, &As[qq * 512]);
        }
        #pragma unroll
        for (int q = 0; q < BN / 32; q++) {
            int qq = w * (BN / 32) + q;
            int m = qq * 8 + srow;
            int cs = schunk ^ (m & 7);
            GLOBAL_LOAD_LDS16(Bb + (size_t)m * Kd + k0 + cs * 8, &Bs[qq * 512]);
        }
        __syncthreads();

        short8 af[FM][2], bfr[FN][2];
        #pragma unroll
        for (int i = 0; i < FM; i++) {
            int ml = wm0 + 16 * i + (lane & 15);
            #pragma unroll
            for (int h = 0; h < 2; h++) {
                int c = (h * 4 + (lane >> 4)) ^ (ml & 7);
                af[i][h] = *(const short8*)&As[ml * 64 + c * 8];
            }
        }
        #pragma unroll
        for (int j = 0; j < FN; j++) {
            int nl = wn0 + 16 * j + (lane & 15);
            #pragma unroll
            for (int h = 0; h < 2; h++) {
                int c = (h * 4 + (lane >> 4)) ^ (nl & 7);
                bfr[j][h] = *(const short8*)&Bs[nl * 64 + c * 8];
            }
        }
        #pragma unroll
        for (int i = 0; i < FM; i++)
            #pragma unroll
            for (int j = 0; j < FN; j++) {
                acc[i][j] = __builtin_amdgcn_mfma_f32_16x16x32_bf16(af[i][0], bfr[j][0], acc[i][j], 0, 0, 0);
                acc[i][j] = __builtin_amdgcn_mfma_f32_16x16x32_bf16(af[i][1], bfr[j][1], acc[i][j], 0, 0, 0);
            }
        __syncthreads();
    }

    if (OUT_MODE == 0) {
        float* Cb = (float*)C + (size_t)z * sC;
        #pragma unroll
        for (int i = 0; i < FM; i++)
            #pragma unroll
            for (int j = 0; j < FN; j++) {
                int row0 = m0 + wm0 + 16 * i + 4 * (lane >> 4);
                int col = n0 + wn0 + 16 * j + (lane & 15);
                #pragma unroll
                for (int r = 0; r < 4; r++)
                    Cb[(size_t)(row0 + r) * ldc + col] = acc[i][j][r];
            }
    } else {
        ushort* Cb = (ushort*)C + (size_t)z * sC;
        #pragma unroll
        for (int i = 0; i < FM; i++)
            #pragma unroll
            for (int j = 0; j < FN; j++) {
                int nn = n0 + wn0 + 16 * j + (lane & 15);
                int mm = m0 + wm0 + 16 * i + 4 * (lane >> 4);
                ushort4_t o = {f2bf(acc[i][j][0]), f2bf(acc[i][j][1]),
                               f2bf(acc[i][j][2]), f2bf(acc[i][j][3])};
                *(ushort4_t*)&Cb[(size_t)nn * ldc + mm] = o;
            }
    }
}

// ---- iteration --------------------------------------------------------------
__global__ __launch_bounds__(256) void init_kernel(
    const float* __restrict__ y, float* __restrict__ r, float* __restrict__ acc)
{
    const int i = blockIdx.x * 256 + threadIdx.x;
    r[i] = y[i];
    acc[i] = 0.f;
}

// One step: acc[rows] += r; r_next[rows] = r[rows] - inv_LP * (M r)[rows]
// 1-D grid of 2048 blocks with XCD-aware remap: block i -> xcd (i&7) serves
// batch b = (i&7) + 8*((i>>3)&7), slice s = i>>6. All 32 slices of batch b
// land on XCD b&7, so each XCD's 4MB L2 holds exactly its 8 batches' M
// (8 x 512KB) across all 24 steps.
__global__ __launch_bounds__(256) void step_kernel(
    const ushort* __restrict__ M, const float* __restrict__ r_cur,
    float* __restrict__ r_next, float* __restrict__ acc)
{
    const int i = blockIdx.x;
    const int b = (i & 7) + 8 * ((i >> 3) & 7);
    const int slice = i >> 6;              // 0..31, rows [slice*16, +16)
    const int tid = threadIdx.x;
    const float inv_LP = 1.0f / ((float)L_ * (float)P_);

    const int row = slice * 16 + (tid >> 4);   // global row
    const int j = tid & 15;                    // 16 lanes per row

    // Prefetch this thread's 4 x 16B M chunks BEFORE the rs barrier
    const ushort* Mr = M + ((size_t)b * P_ + row) * P_;
    ushort8 m8[4];
    #pragma unroll
    for (int q = 0; q < 4; q++)
        m8[q] = *(const ushort8*)&Mr[q * 128 + 8 * j];

    __shared__ float rs[P_];
    *(float2*)&rs[tid * 2] = *(const float2*)&r_cur[b * P_ + tid * 2];
    __syncthreads();

    float s = 0.f;
    #pragma unroll
    for (int q = 0; q < 4; q++) {
        const int c = q * 128 + 8 * j;
        #pragma unroll
        for (int e = 0; e < 8; e++)
            s += bf2f(m8[q][e]) * rs[c + e];
    }
    s += __shfl_xor(s, 1);
    s += __shfl_xor(s, 2);
    s += __shfl_xor(s, 4);
    s += __shfl_xor(s, 8);
    if (j == 0) {
        acc[b * P_ + row] += rs[row];
        r_next[b * P_ + row] = rs[row] - s * inv_LP;
    }
}

// f[b][k] = inv_LP * sum_p G[b][k][p] * acc[b][p]
__global__ __launch_bounds__(256) void final_kernel(
    const float* __restrict__ G, const float* __restrict__ acc, float* __restrict__ f)
{
    const int b = blockIdx.x;
    const int tid = threadIdx.x;
    const float inv_LP = 1.0f / ((float)L_ * (float)P_);

    __shared__ float as[P_];
    for (int p = tid; p < P_; p += 256) as[p] = acc[b * P_ + p];
    __syncthreads();

    const int k = tid >> 2, jj = tid & 3;
    const float* Gb = G + (size_t)b * K_ * P_;
    float s = 0.f;
    for (int p = jj; p < P_; p += 4) s += Gb[k * P_ + p] * as[p];
    s += __shfl_xor(s, 1);
    s += __shfl_xor(s, 2);
    if (jj == 0) f[b * K_ + k] = s * inv_LP;
}

extern "C" void kernel_launch(void* const* d_in, const int* in_sizes, int n_in,
                              void* d_out, int out_size, void* d_ws, size_t ws_size,
                              hipStream_t stream) {
    const float* X     = (const float*)d_in[0];  // (B,D,P)
    const float* Xq    = (const float*)d_in[1];  // (B,D,K)
    const float* y     = (const float*)d_in[2];  // (B,P)
    const float* F     = (const float*)d_in[3];  // (D,D)
    const float* gamma = (const float*)d_in[4];  // (D)
    float* out = (float*)d_out;                  // (B,K)

    float* ws = (float*)d_ws;
    float* G  = ws;                                   // B*K*P fp32
    float* r0 = G + (size_t)B_ * K_ * P_;             // B*P
    float* r1 = r0 + (size_t)B_ * P_;                 // B*P
    float* ac = r1 + (size_t)B_ * P_;                 // B*P
    ushort* Wb  = (ushort*)(ac + (size_t)B_ * P_);    // D*D bf16 (symmetric)
    ushort* Ft  = Wb + (size_t)D_ * D_;               // F^T bf16
    ushort* Fg  = Ft + (size_t)D_ * D_;               // gamma-scaled F^T bf16
    ushort* Xt  = Fg + (size_t)D_ * D_;               // (B,P,D) bf16
    ushort* Xqt = Xt + (size_t)B_ * P_ * D_;          // (B,K,D) bf16
    ushort* Yt  = Xqt + (size_t)B_ * K_ * D_;         // (B,P,D) bf16
    ushort* Mb  = Yt + (size_t)B_ * P_ * D_;          // (B,P,P) bf16 (symmetric)

    // Transposed bf16 operands
    transpose_convert<<<dim3(D_ / 64, D_ / 64, 1), 256, 0, stream>>>(F, Ft, D_, D_, nullptr);
    transpose_convert<<<dim3(D_ / 64, D_ / 64, 1), 256, 0, stream>>>(F, Fg, D_, D_, gamma);
    transpose_convert<<<dim3(P_ / 64, D_ / 64, B_), 256, 0, stream>>>(X, Xt, D_, P_, nullptr);
    transpose_convert<<<dim3(K_ / 64, D_ / 64, B_), 256, 0, stream>>>(Xq, Xqt, D_, K_, nullptr);

    // W[m][n] = sum_k gamma[k] F[k][m] F[k][n]  (bf16 out; symmetric)
    mfma_tn<128, 128, 1><<<dim3(D_ / 128, D_ / 128, 1), 256, 0, stream>>>(
        Fg, 0, Ft, 0, Wb, 0, D_, D_);

    // Yt[b][p][d] = (W X_b)^T
    mfma_tn<128, 128, 1><<<dim3(P_ / 128, D_ / 128, B_), 256, 0, stream>>>(
        Wb, 0, Xt, (long)P_ * D_, Yt, (long)P_ * D_, D_, D_);

    // Mb[b][p][q] = X_b^T Y_b (symmetric)
    mfma_tn<128, 128, 1><<<dim3(P_ / 128, P_ / 128, B_), 256, 0, stream>>>(
        Xt, (long)P_ * D_, Yt, (long)P_ * D_, Mb, (long)P_ * P_, P_, D_);

    // G[b][k][p] fp32
    mfma_tn<64, 128, 0><<<dim3(P_ / 128, K_ / 64, B_), 256, 0, stream>>>(
        Xqt, (long)K_ * D_, Yt, (long)P_ * D_, G, (long)K_ * P_, P_, D_);

    // Iteration: 24 step kernels, XCD-pinned batches (ping-pong r buffers)
    init_kernel<<<dim3(B_ * P_ / 256), 256, 0, stream>>>(y, r0, ac);
    float* rc = r0; float* rn = r1;
    for (int t = 0; t < L_; t++) {
        step_kernel<<<dim3(B_ * P_ / 16), 256, 0, stream>>>(Mb, rc, rn, ac);
        float* tmp = rc; rc = rn; rn = tmp;
    }

    final_kernel<<<dim3(B_), 256, 0, stream>>>(G, ac, out);
}